// Round 3
// baseline (1099.727 us; speedup 1.0000x reference)
//
#include <hip/hip_runtime.h>
#include <hip/hip_bf16.h>
#include <cstdint>

typedef __bf16 bf16;
typedef __bf16 bf16x8 __attribute__((ext_vector_type(8)));
typedef float f32x4 __attribute__((ext_vector_type(4)));
typedef int i32x4 __attribute__((ext_vector_type(4)));

#define HIDC 96
#define CINC 192
#define EPSC 1e-5f

// ---------------------------------------------------------------------------
// K0: repack W_conv [27][192][96] fp32 + W_lin [192][96] fp32 into bf16
// MFMA-B fragment order. dst layout: [off(28)][cix=kc*6+ct (36)][lane(64)][j(8)]
//   element = W[off][k = kc*32 + (lane>>4)*8 + j][col = ct*16 + (lane&15)]
// ---------------------------------------------------------------------------
__global__ void k_repack(const float* __restrict__ Wc, const float* __restrict__ Wl,
                         bf16* __restrict__ dst, int total) {
  int t = blockIdx.x * 256 + threadIdx.x;
  if (t >= total) return;
  int off = t / 18432;
  int rem = t - off * 18432;
  int cix = rem >> 9;
  int lane = (rem >> 3) & 63;
  int j = rem & 7;
  int k = (cix / 6) * 32 + ((lane >> 4) << 3) + j;
  int col = (cix % 6) * 16 + (lane & 15);
  const float* src = (off < 27) ? (Wc + ((size_t)off * CINC + k) * HIDC + col)
                                : (Wl + (size_t)k * HIDC + col);
  dst[t] = (bf16)(*src);
}

// ---------------------------------------------------------------------------
// K1: voxelize scatter-add (fp32 atomics). one thread per (point, channel).
// ---------------------------------------------------------------------------
__global__ void k_voxelize(const float* __restrict__ hid, const float* __restrict__ qry,
                           const int* __restrict__ seg, float* __restrict__ vsum,
                           float* __restrict__ cnt, int Npts) {
  int t = blockIdx.x * 256 + threadIdx.x;
  if (t >= Npts * CINC) return;
  int p = t / CINC;
  int c = t - p * CINC;
  float v = (c < HIDC) ? hid[(size_t)p * HIDC + c] : qry[(size_t)p * HIDC + c - HIDC];
  int s = seg[p];
  atomicAdd(vsum + (size_t)s * CINC + c, v);
  if (c == 0) atomicAdd(cnt + s, 1.0f);
}

// ---------------------------------------------------------------------------
// K2: vfeat = vsum / max(cnt,1) -> bf16, with zero pad row at index M.
// ---------------------------------------------------------------------------
__global__ void k_vfeat(const float* __restrict__ vsum, const float* __restrict__ cnt,
                        bf16* __restrict__ vpad, int M) {
  int t = blockIdx.x * 256 + threadIdx.x;
  if (t >= (M + 1) * CINC) return;
  int v = t / CINC;
  float x = 0.f;
  if (v < M) x = vsum[t] / fmaxf(cnt[v], 1.0f);
  vpad[t] = (bf16)x;
}

// ---------------------------------------------------------------------------
// K3: sparse conv, K-split x3. grid (rowblocks, 3); block b.y does offsets
// [9*b.y, 9*b.y+9) = 18 LDS stages, atomicAdd fp32 partials into accbuf.
// 384 thr = 6 waves; 64 rows/wave; 96 cols. B double-buffered in LDS,
// register-prefetched, one barrier/stage. 3 blocks/CU -> 18 waves/CU.
// ---------------------------------------------------------------------------
__launch_bounds__(384, 4)
__global__ void k_conv(const bf16* __restrict__ vpad, const int* __restrict__ nbr,
                       const bf16* __restrict__ wpack, float* __restrict__ accbuf,
                       int M) {
  __shared__ bf16 Bb[2][9216];  // 2 x 18KB
  const int tid = threadIdx.x;
  const int wave = tid >> 6;
  const int lane = tid & 63;
  const int m = lane & 15;
  const int quad = lane >> 4;
  const int rb = blockIdx.x * 384 + wave * 64;
  const int sbase = blockIdx.y * 18;

  f32x4 acc[4][6];
#pragma unroll
  for (int rt = 0; rt < 4; rt++)
#pragma unroll
    for (int ct = 0; ct < 6; ct++) {
      f32x4 z = {0.f, 0.f, 0.f, 0.f};
      acc[rt][ct] = z;
    }

  const char* wb = (const char*)wpack;
  const size_t lanestage = (size_t)(wave * 3) * 1024 + (size_t)lane * 16;
  i32x4 breg[3];
#pragma unroll
  for (int i = 0; i < 3; i++)
    breg[i] = *(const i32x4*)(wb + (size_t)sbase * 18432 + lanestage + (size_t)i * 1024);

  int gidx[4];
  for (int si = 0; si < 18; si++) {
    const int s = sbase + si;
    const int buf = si & 1;
    {
      char* bbw = (char*)&Bb[buf][0];
#pragma unroll
      for (int i = 0; i < 3; i++)
        *(i32x4*)(bbw + (size_t)(wave * 3 + i) * 1024 + (size_t)lane * 16) = breg[i];
    }
    __syncthreads();
    if (si < 17) {
      const char* src = wb + (size_t)(s + 1) * 18432 + lanestage;
#pragma unroll
      for (int i = 0; i < 3; i++)
        breg[i] = *(const i32x4*)(src + (size_t)i * 1024);
    }
    const int off = s >> 1;
    const int half = s & 1;
    if (half == 0) {
#pragma unroll
      for (int rt = 0; rt < 4; rt++) {
        int r = rb + rt * 16 + m;
        gidx[rt] = (r < M) ? nbr[(size_t)r * 27 + off] : M;  // row M = zero pad
      }
    }
    const char* bbr = (const char*)&Bb[buf][0];
#pragma unroll
    for (int kc2 = 0; kc2 < 3; kc2++) {
      const int kc = half * 3 + kc2;
      bf16x8 af[4];
#pragma unroll
      for (int rt = 0; rt < 4; rt++)
        af[rt] = *(const bf16x8*)(vpad + (size_t)gidx[rt] * CINC + kc * 32 + quad * 8);
#pragma unroll
      for (int ct = 0; ct < 6; ct++) {
        bf16x8 bfm = *(const bf16x8*)(bbr + (size_t)(kc2 * 6 + ct) * 1024 + (size_t)lane * 16);
#pragma unroll
        for (int rt = 0; rt < 4; rt++)
          acc[rt][ct] = __builtin_amdgcn_mfma_f32_16x16x32_bf16(af[rt], bfm, acc[rt][ct], 0, 0, 0);
      }
    }
  }

  // epilogue: atomic-accumulate partials (C layout: row = quad*4+rr, col = lane&15)
#pragma unroll
  for (int rt = 0; rt < 4; rt++) {
#pragma unroll
    for (int rr = 0; rr < 4; rr++) {
      const int r2 = rb + rt * 16 + quad * 4 + rr;
      if (r2 < M) {
        float* dst = accbuf + (size_t)r2 * HIDC + m;
#pragma unroll
        for (int ct = 0; ct < 6; ct++) atomicAdd(dst + ct * 16, acc[rt][ct][rr]);
      }
    }
  }
}

// ---------------------------------------------------------------------------
// K3b: BN stats: column sums + sumsq over accbuf -> bnsum[0:96], bnsum[96:192]
// ---------------------------------------------------------------------------
__global__ void k_bnstat(const float* __restrict__ accbuf, float* __restrict__ bnsum,
                         int M) {
  const int tid = threadIdx.x;  // 192
  const int col = tid % 96;
  const int rp = tid / 96;
  float sv = 0.f, s2 = 0.f;
  for (int r = blockIdx.x * 2 + rp; r < M; r += gridDim.x * 2) {
    float v = accbuf[(size_t)r * HIDC + col];
    sv += v;
    s2 += v * v;
  }
  atomicAdd(bnsum + col, sv);
  atomicAdd(bnsum + 96 + col, s2);
}

// ---------------------------------------------------------------------------
// K4: finalize BN: scale = gamma*rsqrt(var+eps), shift = beta - mu*scale.
// ---------------------------------------------------------------------------
__global__ void k_bnfin(const float* __restrict__ bnsum, const float* __restrict__ gamma,
                        const float* __restrict__ beta, float* __restrict__ ss, int M) {
  int c = threadIdx.x;
  if (c >= 96) return;
  float inv = 1.0f / (float)M;
  float mu = bnsum[c] * inv;
  float var = bnsum[96 + c] * inv - mu * mu;
  var = fmaxf(var, 0.f);
  float sc = gamma[c] * rsqrtf(var + EPSC);
  ss[c] = sc;
  ss[96 + c] = beta[c] - mu * sc;
}

// ---------------------------------------------------------------------------
// K5: y = relu(acc*scale + shift) -> bf16 ypad, zero pad row M.
// ---------------------------------------------------------------------------
__global__ void k_bnapply(const float* __restrict__ accbuf, const float* __restrict__ ss,
                          bf16* __restrict__ ypad, int M) {
  int t = blockIdx.x * 256 + threadIdx.x;
  if (t >= (M + 1) * HIDC) return;
  int v = t / HIDC;
  int c = t - v * HIDC;
  float y = 0.f;
  if (v < M) y = fmaxf(accbuf[t] * ss[c] + ss[96 + c], 0.f);
  ypad[t] = (bf16)y;
}

// ---------------------------------------------------------------------------
// K6: lin = hx @ W_lin + b_lin (fp32 in, bf16 MFMA, bf16 out). LDS-free,
// 256 thr = 4 waves x 32 rows; B fragments direct from L2-resident wlpack.
// ---------------------------------------------------------------------------
__launch_bounds__(256, 4)
__global__ void k_linear(const float* __restrict__ hid, const float* __restrict__ qry,
                         const bf16* __restrict__ wlpack, const float* __restrict__ blin,
                         bf16* __restrict__ lin, int Npts) {
  const int tid = threadIdx.x;
  const int wave = tid >> 6;
  const int lane = tid & 63;
  const int m = lane & 15;
  const int quad = lane >> 4;
  const int rb = blockIdx.x * 128 + wave * 32;

  f32x4 acc[2][6];
#pragma unroll
  for (int rt = 0; rt < 2; rt++)
#pragma unroll
    for (int ct = 0; ct < 6; ct++) {
      f32x4 z = {0.f, 0.f, 0.f, 0.f};
      acc[rt][ct] = z;
    }

  int prow[2];
#pragma unroll
  for (int rt = 0; rt < 2; rt++) {
    int r = rb + rt * 16 + m;
    prow[rt] = (r < Npts) ? r : (Npts - 1);
  }
  const char* wp = (const char*)wlpack;
#pragma unroll
  for (int kc = 0; kc < 6; kc++) {
    const float* srcA = (kc < 3) ? (hid + kc * 32) : (qry + (kc - 3) * 32);
    bf16x8 af[2];
#pragma unroll
    for (int rt = 0; rt < 2; rt++) {
      const float* pA = srcA + (size_t)prow[rt] * HIDC + quad * 8;
      f32x4 lo = *(const f32x4*)pA;
      f32x4 hi = *(const f32x4*)(pA + 4);
#pragma unroll
      for (int j = 0; j < 4; j++) {
        af[rt][j] = (bf16)lo[j];
        af[rt][4 + j] = (bf16)hi[j];
      }
    }
#pragma unroll
    for (int ct = 0; ct < 6; ct++) {
      bf16x8 bfm = *(const bf16x8*)(wp + (size_t)((kc * 6 + ct) * 64 + lane) * 16);
#pragma unroll
      for (int rt = 0; rt < 2; rt++)
        acc[rt][ct] = __builtin_amdgcn_mfma_f32_16x16x32_bf16(af[rt], bfm, acc[rt][ct], 0, 0, 0);
    }
  }
  float bl[6];
#pragma unroll
  for (int ct = 0; ct < 6; ct++) bl[ct] = blin[ct * 16 + m];
#pragma unroll
  for (int rt = 0; rt < 2; rt++)
#pragma unroll
    for (int rr = 0; rr < 4; rr++) {
      const int r2 = rb + rt * 16 + quad * 4 + rr;
      if (r2 < Npts) {
        bf16* dst = lin + (size_t)r2 * HIDC + m;
#pragma unroll
        for (int ct = 0; ct < 6; ct++)
          dst[ct * 16] = (bf16)(acc[rt][ct][rr] + bl[ct]);
      }
    }
}

// ---------------------------------------------------------------------------
// K7: out = lin + sum_k w[p,k] * ypad[cidx[p,k]]  (8-channel groups)
// ---------------------------------------------------------------------------
__global__ void k_out(const bf16* __restrict__ lin, const bf16* __restrict__ ypad,
                      const float* __restrict__ cw, const int* __restrict__ cidx,
                      float* __restrict__ out, int Npts) {
  int t = blockIdx.x * 256 + threadIdx.x;
  if (t >= Npts * 12) return;
  int p = t / 12;
  int g = t - p * 12;
  float a[8];
  bf16x8 lv = *(const bf16x8*)(lin + (size_t)p * HIDC + g * 8);
#pragma unroll
  for (int j = 0; j < 8; j++) a[j] = (float)lv[j];
  f32x4 w0 = *(const f32x4*)(cw + (size_t)p * 8);
  f32x4 w1 = *(const f32x4*)(cw + (size_t)p * 8 + 4);
  const i32x4* cp = (const i32x4*)(cidx + (size_t)p * 8);
  i32x4 c0 = cp[0], c1 = cp[1];
#pragma unroll
  for (int k = 0; k < 8; k++) {
    int idx = (k < 4) ? c0[k] : c1[k - 4];
    float wk = (k < 4) ? w0[k] : w1[k - 4];
    bf16x8 yv = *(const bf16x8*)(ypad + (size_t)idx * HIDC + g * 8);
#pragma unroll
    for (int j = 0; j < 8; j++) a[j] += wk * (float)yv[j];
  }
  float* op = out + (size_t)p * HIDC + g * 8;
  f32x4 s0, s1;
#pragma unroll
  for (int j = 0; j < 4; j++) { s0[j] = a[j]; s1[j] = a[4 + j]; }
  *(f32x4*)op = s0;
  *(f32x4*)(op + 4) = s1;
}

// ---------------------------------------------------------------------------
extern "C" void kernel_launch(void* const* d_in, const int* in_sizes, int n_in,
                              void* d_out, int out_size, void* d_ws, size_t ws_size,
                              hipStream_t stream) {
  const float* hid = (const float*)d_in[0];
  const float* qry = (const float*)d_in[1];
  const float* Wc = (const float*)d_in[2];
  const float* gamma = (const float*)d_in[3];
  const float* beta = (const float*)d_in[4];
  const float* Wl = (const float*)d_in[5];
  const float* blin = (const float*)d_in[6];
  const float* cw = (const float*)d_in[7];
  const int* seg = (const int*)d_in[8];
  const int* nbr = (const int*)d_in[9];
  const int* cidx = (const int*)d_in[10];
  float* out = (float*)d_out;
  const int Npts = in_sizes[0] / HIDC;
  const int M = in_sizes[9] / 27;

  // ---- workspace layout with overlays (same footprint as round 2) ----
  // region A (M*192*4 bytes): vsum fp32 [M,192] (K1-K2)
  //   -> accbuf fp32 [M,96] at +0 (K3..K5, zeroed by memset#2 after vfeat)
  //   -> lin bf16 [N,96] at +M*96*4 (K6-K7); 37MB + 23MB <= 74MB
  // region B: vpad bf16 [M+1,192] -> ypad bf16 [M+1,96]
  char* ws = (char*)d_ws;
  size_t cur = 0;
  auto alloc = [&](size_t b) { size_t o = cur; cur = (cur + b + 255) & ~(size_t)255; return o; };
  size_t RA = (size_t)M * CINC * 4;
  size_t needA = (size_t)M * HIDC * 4 + (size_t)Npts * HIDC * 2;
  if (needA > RA) RA = needA;
  size_t o_A = alloc(RA);
  size_t o_cnt = alloc((size_t)M * 4);
  size_t o_bn = alloc(192 * 4);
  size_t o_ss = alloc(192 * 4);
  size_t o_B = alloc((size_t)(M + 1) * CINC * 2);
  size_t o_wpack = alloc((size_t)28 * 18432 * 2);
  (void)ws_size; (void)n_in; (void)out_size;

  float* vsum = (float*)(ws + o_A);
  float* accbuf = (float*)(ws + o_A);
  bf16* lin = (bf16*)(ws + o_A + (size_t)M * HIDC * 4);
  float* cnt = (float*)(ws + o_cnt);
  float* bnsum = (float*)(ws + o_bn);
  float* ss = (float*)(ws + o_ss);
  bf16* vpad = (bf16*)(ws + o_B);
  bf16* ypad = (bf16*)(ws + o_B);
  bf16* wpack = (bf16*)(ws + o_wpack);
  bf16* wlpack = wpack + (size_t)27 * 18432;

  // memset#1: zero vsum + cnt + bnsum (ws poisoned 0xAA each call)
  hipMemsetAsync(ws, 0, o_bn + 192 * 4, stream);

  int totalRepack = 28 * 18432;
  k_repack<<<(totalRepack + 255) / 256, 256, 0, stream>>>(Wc, Wl, wpack, totalRepack);
  k_voxelize<<<(Npts * CINC + 255) / 256, 256, 0, stream>>>(hid, qry, seg, vsum, cnt, Npts);
  k_vfeat<<<((M + 1) * CINC + 255) / 256, 256, 0, stream>>>(vsum, cnt, vpad, M);
  // memset#2: zero accbuf (overlays now-dead vsum)
  hipMemsetAsync(accbuf, 0, (size_t)M * HIDC * 4, stream);
  dim3 cgrid((M + 383) / 384, 3);
  k_conv<<<cgrid, 384, 0, stream>>>(vpad, nbr, wpack, accbuf, M);
  k_bnstat<<<256, 192, 0, stream>>>(accbuf, bnsum, M);
  k_bnfin<<<1, 128, 0, stream>>>(bnsum, gamma, beta, ss, M);
  k_bnapply<<<((M + 1) * HIDC + 255) / 256, 256, 0, stream>>>(accbuf, ss, ypad, M);
  k_linear<<<(Npts + 127) / 128, 256, 0, stream>>>(hid, qry, wlpack, blin, lin, Npts);
  k_out<<<(Npts * 12 + 255) / 256, 256, 0, stream>>>(lin, ypad, cw, cidx, out, Npts);
}

// Round 4
// 502.752 us; speedup vs baseline: 2.1874x; 2.1874x over previous
//
#include <hip/hip_runtime.h>
#include <hip/hip_bf16.h>
#include <cstdint>

typedef __bf16 bf16;
typedef __bf16 bf16x8 __attribute__((ext_vector_type(8)));
typedef float f32x4 __attribute__((ext_vector_type(4)));
typedef int i32x4 __attribute__((ext_vector_type(4)));

#define HIDC 96
#define CINC 192
#define EPSC 1e-5f

// wpack layout: 56 stages (28 offs x 2 halves) x 20480 B. Real payload per
// stage = 18 cix x 1024 B = 18432 B (+2048 B pad so staging is a uniform
// 5 x 16B chunks per thread for 256 threads). Element within stage:
//   [cix_local(18)][lane(64)][j(8)] bf16, cix = kc*6+ct, half = cix>=18.
//   W[off][k = kc*32 + (lane>>4)*8 + j][col = ct*16 + (lane&15)]
#define STG_B 20480
#define STG_ELEM 10240

// ---------------------------------------------------------------------------
// K0: repack W_conv [27][192][96] fp32 + W_lin [192][96] fp32 -> bf16 wpack.
// ---------------------------------------------------------------------------
__global__ void k_repack(const float* __restrict__ Wc, const float* __restrict__ Wl,
                         bf16* __restrict__ dst, int total) {
  int t = blockIdx.x * 256 + threadIdx.x;
  if (t >= total) return;              // total = 28*18432 real elements
  int off = t / 18432;
  int rem = t - off * 18432;
  int cix = rem >> 9;
  int lane = (rem >> 3) & 63;
  int j = rem & 7;
  int k = (cix / 6) * 32 + ((lane >> 4) << 3) + j;
  int col = (cix % 6) * 16 + (lane & 15);
  const float* src = (off < 27) ? (Wc + ((size_t)off * CINC + k) * HIDC + col)
                                : (Wl + (size_t)k * HIDC + col);
  int half = (cix >= 18) ? 1 : 0;
  size_t de = (size_t)(off * 2 + half) * STG_ELEM + (size_t)(rem - half * 9216);
  dst[de] = (bf16)(*src);
}

// ---------------------------------------------------------------------------
// K1: voxelize scatter-add (fp32 atomics). one thread per (point, channel).
// ---------------------------------------------------------------------------
__global__ void k_voxelize(const float* __restrict__ hid, const float* __restrict__ qry,
                           const int* __restrict__ seg, float* __restrict__ vsum,
                           float* __restrict__ cnt, int Npts) {
  int t = blockIdx.x * 256 + threadIdx.x;
  if (t >= Npts * CINC) return;
  int p = t / CINC;
  int c = t - p * CINC;
  float v = (c < HIDC) ? hid[(size_t)p * HIDC + c] : qry[(size_t)p * HIDC + c - HIDC];
  int s = seg[p];
  atomicAdd(vsum + (size_t)s * CINC + c, v);
  if (c == 0) atomicAdd(cnt + s, 1.0f);
}

// ---------------------------------------------------------------------------
// K2: vfeat = vsum / max(cnt,1) -> bf16, with zero pad row at index M.
// ---------------------------------------------------------------------------
__global__ void k_vfeat(const float* __restrict__ vsum, const float* __restrict__ cnt,
                        bf16* __restrict__ vpad, int M) {
  int t = blockIdx.x * 256 + threadIdx.x;
  if (t >= (M + 1) * CINC) return;
  int v = t / CINC;
  float x = 0.f;
  if (v < M) x = vsum[t] / fmaxf(cnt[v], 1.0f);
  vpad[t] = (bf16)x;
}

// ---------------------------------------------------------------------------
// K3: sparse conv. 256 thr = 4 waves x 32 rows = 128 rows/block -> 750 blocks,
// ~4 blocks/CU (LDS 40KB, VGPR<=128). Each block owns its rows end-to-end:
// all 27 offsets, plain stores, NO global atomics. B double-buffered in LDS
// (20KB stages, 5x16B chunks/thread), register-prefetched, 1 barrier/stage.
// XCD-swizzled blockIdx for vpad L2 locality.
// ---------------------------------------------------------------------------
__launch_bounds__(256, 4)
__global__ void k_conv(const bf16* __restrict__ vpad, const int* __restrict__ nbr,
                       const bf16* __restrict__ wpack, float* __restrict__ accbuf,
                       int M, int nblk, int nper) {
  // swizzle: give each XCD a contiguous row range (dispatch is round-robin % 8)
  const int bx = (int)(blockIdx.x & 7) * nper + (int)(blockIdx.x >> 3);
  if (bx >= nblk) return;
  __shared__ bf16 Bb[2][STG_B / 2];  // 2 x 20KB
  const int tid = threadIdx.x;
  const int wave = tid >> 6;
  const int lane = tid & 63;
  const int m = lane & 15;
  const int quad = lane >> 4;
  const int rb = bx * 128 + wave * 32;

  f32x4 acc[2][6];
#pragma unroll
  for (int rt = 0; rt < 2; rt++)
#pragma unroll
    for (int ct = 0; ct < 6; ct++) {
      f32x4 z = {0.f, 0.f, 0.f, 0.f};
      acc[rt][ct] = z;
    }

  const char* wb = (const char*)wpack;
  i32x4 breg[5];
#pragma unroll
  for (int i = 0; i < 5; i++)
    breg[i] = *(const i32x4*)(wb + (size_t)(tid + 256 * i) * 16);

  int gidx[2];
  for (int s = 0; s < 54; s++) {
    const int buf = s & 1;
    {
      char* bbw = (char*)&Bb[buf][0];
#pragma unroll
      for (int i = 0; i < 5; i++)
        *(i32x4*)(bbw + (size_t)(tid + 256 * i) * 16) = breg[i];
    }
    __syncthreads();
    if (s < 53) {
      const char* src = wb + (size_t)(s + 1) * STG_B;
#pragma unroll
      for (int i = 0; i < 5; i++)
        breg[i] = *(const i32x4*)(src + (size_t)(tid + 256 * i) * 16);
    }
    const int off = s >> 1;
    const int half = s & 1;
    if (half == 0) {
#pragma unroll
      for (int rt = 0; rt < 2; rt++) {
        int r = rb + rt * 16 + m;
        gidx[rt] = (r < M) ? nbr[(size_t)r * 27 + off] : M;  // row M = zero pad
      }
    }
    const char* bbr = (const char*)&Bb[buf][0];
#pragma unroll
    for (int kc2 = 0; kc2 < 3; kc2++) {
      const int kc = half * 3 + kc2;
      bf16x8 af[2];
#pragma unroll
      for (int rt = 0; rt < 2; rt++)
        af[rt] = *(const bf16x8*)(vpad + (size_t)gidx[rt] * CINC + kc * 32 + quad * 8);
#pragma unroll
      for (int ct = 0; ct < 6; ct++) {
        bf16x8 bfm = *(const bf16x8*)(bbr + (size_t)(kc2 * 6 + ct) * 1024 + (size_t)lane * 16);
#pragma unroll
        for (int rt = 0; rt < 2; rt++)
          acc[rt][ct] = __builtin_amdgcn_mfma_f32_16x16x32_bf16(af[rt], bfm, acc[rt][ct], 0, 0, 0);
      }
    }
  }

  // epilogue: plain stores (C layout: row = quad*4+rr, col = lane&15)
#pragma unroll
  for (int rt = 0; rt < 2; rt++) {
#pragma unroll
    for (int rr = 0; rr < 4; rr++) {
      const int r2 = rb + rt * 16 + quad * 4 + rr;
      if (r2 < M) {
        float* dst = accbuf + (size_t)r2 * HIDC + m;
#pragma unroll
        for (int ct = 0; ct < 6; ct++) dst[ct * 16] = acc[rt][ct][rr];
      }
    }
  }
}

// ---------------------------------------------------------------------------
// K3b: BN stats: column sums + sumsq over accbuf -> bnsum[0:96], bnsum[96:192]
// ---------------------------------------------------------------------------
__global__ void k_bnstat(const float* __restrict__ accbuf, float* __restrict__ bnsum,
                         int M) {
  const int tid = threadIdx.x;  // 192
  const int col = tid % 96;
  const int rp = tid / 96;
  float sv = 0.f, s2 = 0.f;
  for (int r = blockIdx.x * 2 + rp; r < M; r += gridDim.x * 2) {
    float v = accbuf[(size_t)r * HIDC + col];
    sv += v;
    s2 += v * v;
  }
  atomicAdd(bnsum + col, sv);
  atomicAdd(bnsum + 96 + col, s2);
}

// ---------------------------------------------------------------------------
// K4: finalize BN: scale = gamma*rsqrt(var+eps), shift = beta - mu*scale.
// ---------------------------------------------------------------------------
__global__ void k_bnfin(const float* __restrict__ bnsum, const float* __restrict__ gamma,
                        const float* __restrict__ beta, float* __restrict__ ss, int M) {
  int c = threadIdx.x;
  if (c >= 96) return;
  float inv = 1.0f / (float)M;
  float mu = bnsum[c] * inv;
  float var = bnsum[96 + c] * inv - mu * mu;
  var = fmaxf(var, 0.f);
  float sc = gamma[c] * rsqrtf(var + EPSC);
  ss[c] = sc;
  ss[96 + c] = beta[c] - mu * sc;
}

// ---------------------------------------------------------------------------
// K5: y = relu(acc*scale + shift) -> bf16 ypad, zero pad row M.
// ---------------------------------------------------------------------------
__global__ void k_bnapply(const float* __restrict__ accbuf, const float* __restrict__ ss,
                          bf16* __restrict__ ypad, int M) {
  int t = blockIdx.x * 256 + threadIdx.x;
  if (t >= (M + 1) * HIDC) return;
  int v = t / HIDC;
  int c = t - v * HIDC;
  float y = 0.f;
  if (v < M) y = fmaxf(accbuf[t] * ss[c] + ss[96 + c], 0.f);
  ypad[t] = (bf16)y;
}

// ---------------------------------------------------------------------------
// K6: lin = hx @ W_lin + b_lin (fp32 in, bf16 MFMA, bf16 out). LDS-free,
// 256 thr = 4 waves x 32 rows; B fragments direct from L2-resident wlpack
// (stage-padded layout: half = kc>=3).
// ---------------------------------------------------------------------------
__launch_bounds__(256, 4)
__global__ void k_linear(const float* __restrict__ hid, const float* __restrict__ qry,
                         const bf16* __restrict__ wlpack, const float* __restrict__ blin,
                         bf16* __restrict__ lin, int Npts) {
  const int tid = threadIdx.x;
  const int wave = tid >> 6;
  const int lane = tid & 63;
  const int m = lane & 15;
  const int quad = lane >> 4;
  const int rb = blockIdx.x * 128 + wave * 32;

  f32x4 acc[2][6];
#pragma unroll
  for (int rt = 0; rt < 2; rt++)
#pragma unroll
    for (int ct = 0; ct < 6; ct++) {
      f32x4 z = {0.f, 0.f, 0.f, 0.f};
      acc[rt][ct] = z;
    }

  int prow[2];
#pragma unroll
  for (int rt = 0; rt < 2; rt++) {
    int r = rb + rt * 16 + m;
    prow[rt] = (r < Npts) ? r : (Npts - 1);
  }
  const char* wp = (const char*)wlpack;
#pragma unroll
  for (int kc = 0; kc < 6; kc++) {
    const float* srcA = (kc < 3) ? (hid + kc * 32) : (qry + (kc - 3) * 32);
    bf16x8 af[2];
#pragma unroll
    for (int rt = 0; rt < 2; rt++) {
      const float* pA = srcA + (size_t)prow[rt] * HIDC + quad * 8;
      f32x4 lo = *(const f32x4*)pA;
      f32x4 hi = *(const f32x4*)(pA + 4);
#pragma unroll
      for (int j = 0; j < 4; j++) {
        af[rt][j] = (bf16)lo[j];
        af[rt][4 + j] = (bf16)hi[j];
      }
    }
    const int half = (kc >= 3) ? 1 : 0;
    const int kcl = kc - half * 3;
#pragma unroll
    for (int ct = 0; ct < 6; ct++) {
      bf16x8 bfm = *(const bf16x8*)(wp + (size_t)half * STG_B +
                                    (size_t)((kcl * 6 + ct) * 64 + lane) * 16);
#pragma unroll
      for (int rt = 0; rt < 2; rt++)
        acc[rt][ct] = __builtin_amdgcn_mfma_f32_16x16x32_bf16(af[rt], bfm, acc[rt][ct], 0, 0, 0);
    }
  }
  float bl[6];
#pragma unroll
  for (int ct = 0; ct < 6; ct++) bl[ct] = blin[ct * 16 + m];
#pragma unroll
  for (int rt = 0; rt < 2; rt++)
#pragma unroll
    for (int rr = 0; rr < 4; rr++) {
      const int r2 = rb + rt * 16 + quad * 4 + rr;
      if (r2 < Npts) {
        bf16* dst = lin + (size_t)r2 * HIDC + m;
#pragma unroll
        for (int ct = 0; ct < 6; ct++)
          dst[ct * 16] = (bf16)(acc[rt][ct][rr] + bl[ct]);
      }
    }
}

// ---------------------------------------------------------------------------
// K7: out = lin + sum_k w[p,k] * ypad[cidx[p,k]]  (8-channel groups)
// ---------------------------------------------------------------------------
__global__ void k_out(const bf16* __restrict__ lin, const bf16* __restrict__ ypad,
                      const float* __restrict__ cw, const int* __restrict__ cidx,
                      float* __restrict__ out, int Npts) {
  int t = blockIdx.x * 256 + threadIdx.x;
  if (t >= Npts * 12) return;
  int p = t / 12;
  int g = t - p * 12;
  float a[8];
  bf16x8 lv = *(const bf16x8*)(lin + (size_t)p * HIDC + g * 8);
#pragma unroll
  for (int j = 0; j < 8; j++) a[j] = (float)lv[j];
  f32x4 w0 = *(const f32x4*)(cw + (size_t)p * 8);
  f32x4 w1 = *(const f32x4*)(cw + (size_t)p * 8 + 4);
  const i32x4* cp = (const i32x4*)(cidx + (size_t)p * 8);
  i32x4 c0 = cp[0], c1 = cp[1];
#pragma unroll
  for (int k = 0; k < 8; k++) {
    int idx = (k < 4) ? c0[k] : c1[k - 4];
    float wk = (k < 4) ? w0[k] : w1[k - 4];
    bf16x8 yv = *(const bf16x8*)(ypad + (size_t)idx * HIDC + g * 8);
#pragma unroll
    for (int j = 0; j < 8; j++) a[j] += wk * (float)yv[j];
  }
  float* op = out + (size_t)p * HIDC + g * 8;
  f32x4 s0, s1;
#pragma unroll
  for (int j = 0; j < 4; j++) { s0[j] = a[j]; s1[j] = a[4 + j]; }
  *(f32x4*)op = s0;
  *(f32x4*)(op + 4) = s1;
}

// ---------------------------------------------------------------------------
extern "C" void kernel_launch(void* const* d_in, const int* in_sizes, int n_in,
                              void* d_out, int out_size, void* d_ws, size_t ws_size,
                              hipStream_t stream) {
  const float* hid = (const float*)d_in[0];
  const float* qry = (const float*)d_in[1];
  const float* Wc = (const float*)d_in[2];
  const float* gamma = (const float*)d_in[3];
  const float* beta = (const float*)d_in[4];
  const float* Wl = (const float*)d_in[5];
  const float* blin = (const float*)d_in[6];
  const float* cw = (const float*)d_in[7];
  const int* seg = (const int*)d_in[8];
  const int* nbr = (const int*)d_in[9];
  const int* cidx = (const int*)d_in[10];
  float* out = (float*)d_out;
  const int Npts = in_sizes[0] / HIDC;
  const int M = in_sizes[9] / 27;

  // ---- workspace layout with overlays ----
  // region A: vsum fp32 [M,192] (K1-K2) -> accbuf fp32 [M,96] at +0 (K3..K5,
  //   fully written by k_conv, no memset needed) -> lin bf16 [N,96] at
  //   +M*96*4 (K6-K7)
  // region B: vpad bf16 [M+1,192] -> ypad bf16 [M+1,96] (overlay)
  char* ws = (char*)d_ws;
  size_t cur = 0;
  auto alloc = [&](size_t b) { size_t o = cur; cur = (cur + b + 255) & ~(size_t)255; return o; };
  size_t RA = (size_t)M * CINC * 4;
  size_t needA = (size_t)M * HIDC * 4 + (size_t)Npts * HIDC * 2;
  if (needA > RA) RA = needA;
  size_t o_A = alloc(RA);
  size_t o_cnt = alloc((size_t)M * 4);
  size_t o_bn = alloc(192 * 4);
  size_t o_ss = alloc(192 * 4);
  size_t o_B = alloc((size_t)(M + 1) * CINC * 2);
  size_t o_wpack = alloc((size_t)56 * STG_B);  // ~1.1 MB incl. stage pads
  (void)ws_size; (void)n_in; (void)out_size;

  float* vsum = (float*)(ws + o_A);
  float* accbuf = (float*)(ws + o_A);
  bf16* lin = (bf16*)(ws + o_A + (size_t)M * HIDC * 4);
  float* cnt = (float*)(ws + o_cnt);
  float* bnsum = (float*)(ws + o_bn);
  float* ss = (float*)(ws + o_ss);
  bf16* vpad = (bf16*)(ws + o_B);
  bf16* ypad = (bf16*)(ws + o_B);
  bf16* wpack = (bf16*)(ws + o_wpack);
  bf16* wlpack = (bf16*)(ws + o_wpack + (size_t)54 * STG_B);

  // zero vsum + cnt + bnsum (ws poisoned 0xAA each call)
  hipMemsetAsync(ws, 0, o_bn + 192 * 4, stream);

  int totalRepack = 28 * 18432;
  k_repack<<<(totalRepack + 255) / 256, 256, 0, stream>>>(Wc, Wl, wpack, totalRepack);
  k_voxelize<<<(Npts * CINC + 255) / 256, 256, 0, stream>>>(hid, qry, seg, vsum, cnt, Npts);
  k_vfeat<<<((M + 1) * CINC + 255) / 256, 256, 0, stream>>>(vsum, cnt, vpad, M);
  int nblk = (M + 127) / 128;
  int nper = (nblk + 7) / 8;
  k_conv<<<nper * 8, 256, 0, stream>>>(vpad, nbr, wpack, accbuf, M, nblk, nper);
  k_bnstat<<<256, 192, 0, stream>>>(accbuf, bnsum, M);
  k_bnfin<<<1, 128, 0, stream>>>(bnsum, gamma, beta, ss, M);
  k_bnapply<<<((M + 1) * HIDC + 255) / 256, 256, 0, stream>>>(accbuf, ss, ypad, M);
  k_linear<<<(Npts + 127) / 128, 256, 0, stream>>>(hid, qry, wlpack, blin, lin, Npts);
  k_out<<<(Npts * 12 + 255) / 256, 256, 0, stream>>>(lin, ypad, cw, cidx, out, Npts);
}

// Round 5
// 446.440 us; speedup vs baseline: 2.4633x; 1.1261x over previous
//
#include <hip/hip_runtime.h>
#include <hip/hip_bf16.h>
#include <cstdint>

typedef __bf16 bf16;
typedef __bf16 bf16x8 __attribute__((ext_vector_type(8)));
typedef __bf16 bf16x4 __attribute__((ext_vector_type(4)));
typedef float f32x4 __attribute__((ext_vector_type(4)));
typedef int i32x4 __attribute__((ext_vector_type(4)));

#define HIDC 96
#define CINC 192
#define EPSC 1e-5f

// wpack layout: 56 stages (28 offs x 2 halves) x 20480 B. Real payload per
// stage = 18 cix x 1024 B = 18432 B (+2048 B pad -> uniform 5x16B chunks per
// thread at 256 threads). cix = kc_local*6+ct, element =
//   W[off][k = (half*3+kc_local)*32 + (lane>>4)*8 + j][col = ct*16 + (lane&15)]
#define STG_B 20480
#define STG_ELEM 10240

// ---------------------------------------------------------------------------
// K0: repack W_conv [27][192][96] fp32 + W_lin [192][96] fp32 -> bf16 wpack.
// ---------------------------------------------------------------------------
__global__ void k_repack(const float* __restrict__ Wc, const float* __restrict__ Wl,
                         bf16* __restrict__ dst, int total) {
  int t = blockIdx.x * 256 + threadIdx.x;
  if (t >= total) return;              // total = 28*18432 real elements
  int off = t / 18432;
  int rem = t - off * 18432;
  int cix = rem >> 9;
  int lane = (rem >> 3) & 63;
  int j = rem & 7;
  int k = (cix / 6) * 32 + ((lane >> 4) << 3) + j;
  int col = (cix % 6) * 16 + (lane & 15);
  const float* src = (off < 27) ? (Wc + ((size_t)off * CINC + k) * HIDC + col)
                                : (Wl + (size_t)k * HIDC + col);
  int half = (cix >= 18) ? 1 : 0;
  size_t de = (size_t)(off * 2 + half) * STG_ELEM + (size_t)(rem - half * 9216);
  dst[de] = (bf16)(*src);
}

// ---------------------------------------------------------------------------
// Voxelize path: counting-sort + gather-mean (replaces 23M fp32 atomics).
// ---------------------------------------------------------------------------
__global__ void k_count(const int* __restrict__ seg, int* __restrict__ cnt, int Npts) {
  int t = blockIdx.x * 256 + threadIdx.x;
  if (t < Npts) atomicAdd(cnt + seg[t], 1);
}

__global__ void k_bsum(const int* __restrict__ cnt, int* __restrict__ bsum, int M) {
  __shared__ int sm[256];
  int i = blockIdx.x * 256 + threadIdx.x;
  sm[threadIdx.x] = (i < M) ? cnt[i] : 0;
  __syncthreads();
  for (int st = 128; st > 0; st >>= 1) {
    if (threadIdx.x < st) sm[threadIdx.x] += sm[threadIdx.x + st];
    __syncthreads();
  }
  if (threadIdx.x == 0) bsum[blockIdx.x] = sm[0];
}

// exclusive scan of nb (<=1024) block sums, in place
__global__ void k_bscan(int* __restrict__ bsum, int nb) {
  __shared__ int sm[1024];
  int i = threadIdx.x;
  int v = (i < nb) ? bsum[i] : 0;
  sm[i] = v;
  __syncthreads();
  for (int st = 1; st < 1024; st <<= 1) {
    int t = (i >= st) ? sm[i - st] : 0;
    __syncthreads();
    sm[i] += t;
    __syncthreads();
  }
  if (i < nb) bsum[i] = sm[i] - v;
}

__global__ void k_ptr(const int* __restrict__ cnt, const int* __restrict__ bsum,
                      int* __restrict__ ptr, int* __restrict__ cursor, int M) {
  __shared__ int sm[256];
  int i = blockIdx.x * 256 + threadIdx.x;
  int v = (i < M) ? cnt[i] : 0;
  sm[threadIdx.x] = v;
  __syncthreads();
  for (int st = 1; st < 256; st <<= 1) {
    int t = (threadIdx.x >= st) ? sm[threadIdx.x - st] : 0;
    __syncthreads();
    sm[threadIdx.x] += t;
    __syncthreads();
  }
  if (i < M) {
    int e = bsum[blockIdx.x] + sm[threadIdx.x] - v;
    ptr[i] = e;
    cursor[i] = e;
  }
}

__global__ void k_scatter(const int* __restrict__ seg, int* __restrict__ cursor,
                          int* __restrict__ plist, int Npts) {
  int t = blockIdx.x * 256 + threadIdx.x;
  if (t < Npts) {
    int pos = atomicAdd(cursor + seg[t], 1);
    plist[pos] = t;
  }
}

// per (voxel, 4-channel group): mean of member point features -> bf16 vpad.
__global__ void k_gmean(const float* __restrict__ hid, const float* __restrict__ qry,
                        const int* __restrict__ ptr, const int* __restrict__ cnt,
                        const int* __restrict__ plist, bf16* __restrict__ vpad, int M) {
  int t = blockIdx.x * 256 + threadIdx.x;
  if (t >= (M + 1) * 48) return;
  int v = t / 48;
  int q = t - v * 48;
  f32x4 a = {0.f, 0.f, 0.f, 0.f};
  if (v < M) {
    int st = ptr[v], n = cnt[v];
    const float* base = (q < 24) ? (hid + q * 4) : (qry + (q - 24) * 4);
    for (int j = 0; j < n; j++) {
      int p = plist[st + j];
      a += *(const f32x4*)(base + (size_t)p * HIDC);
    }
    a *= (1.0f / (float)(n > 0 ? n : 1));
  }
  bf16x4 o;
#pragma unroll
  for (int j = 0; j < 4; j++) o[j] = (bf16)a[j];
  *(bf16x4*)(vpad + (size_t)v * CINC + q * 4) = o;
}

// ---------------------------------------------------------------------------
// K3: sparse conv. 256 thr = 4 waves x 32 rows = 128 rows/block. Each block
// owns its rows end-to-end (plain stores, no atomics). B double-buffered in
// LDS, register-prefetched; A-fragments + nbr indices software-pipelined one
// stage ahead in registers so the gather latency overlaps the MFMAs.
// ---------------------------------------------------------------------------
__launch_bounds__(256, 3)
__global__ void k_conv(const bf16* __restrict__ vpad, const int* __restrict__ nbr,
                       const bf16* __restrict__ wpack, float* __restrict__ accbuf,
                       int M, int nblk, int nper) {
  const int bx = (int)(blockIdx.x & 7) * nper + (int)(blockIdx.x >> 3);
  if (bx >= nblk) return;
  __shared__ bf16 Bb[2][STG_B / 2];  // 2 x 20KB
  const int tid = threadIdx.x;
  const int wave = tid >> 6;
  const int lane = tid & 63;
  const int m = lane & 15;
  const int quad = lane >> 4;
  const int rb = bx * 128 + wave * 32;

  f32x4 acc[2][6];
#pragma unroll
  for (int rt = 0; rt < 2; rt++)
#pragma unroll
    for (int ct = 0; ct < 6; ct++) {
      f32x4 z = {0.f, 0.f, 0.f, 0.f};
      acc[rt][ct] = z;
    }

  const char* wb = (const char*)wpack;
  i32x4 breg[5];
#pragma unroll
  for (int i = 0; i < 5; i++)
    breg[i] = *(const i32x4*)(wb + (size_t)(tid + 256 * i) * 16);

  // prologue: gidx for offset 0, A-frags for stage 0 (half0 -> kc 0..2)
  int gidx[2], gidx2[2];
#pragma unroll
  for (int rt = 0; rt < 2; rt++) {
    int r = rb + rt * 16 + m;
    gidx[rt] = (r < M) ? nbr[(size_t)r * 27] : M;
  }
  bf16x8 afn[2][3];
#pragma unroll
  for (int kc2 = 0; kc2 < 3; kc2++)
#pragma unroll
    for (int rt = 0; rt < 2; rt++)
      afn[rt][kc2] = *(const bf16x8*)(vpad + (size_t)gidx[rt] * CINC + kc2 * 32 + quad * 8);

  for (int s = 0; s < 54; s++) {
    const int buf = s & 1;
    {
      char* bbw = (char*)&Bb[buf][0];
#pragma unroll
      for (int i = 0; i < 5; i++)
        *(i32x4*)(bbw + (size_t)(tid + 256 * i) * 16) = breg[i];
    }
    __syncthreads();
    if (s < 53) {
      const char* src = wb + (size_t)(s + 1) * STG_B;
#pragma unroll
      for (int i = 0; i < 5; i++)
        breg[i] = *(const i32x4*)(src + (size_t)(tid + 256 * i) * 16);
    }
    // take the prefetched A-frags for this stage
    bf16x8 afc[2][3];
#pragma unroll
    for (int kc2 = 0; kc2 < 3; kc2++)
#pragma unroll
      for (int rt = 0; rt < 2; rt++) afc[rt][kc2] = afn[rt][kc2];

    const int half = s & 1;
    const int off = s >> 1;
    if (half == 0) {
      // prefetch nbr for off+1 (used one stage later)
      const int offn = off + 1;
#pragma unroll
      for (int rt = 0; rt < 2; rt++) {
        int r = rb + rt * 16 + m;
        gidx2[rt] = (r < M && offn < 27) ? nbr[(size_t)r * 27 + offn] : M;
      }
      // prefetch A for stage s+1 (half1 of same off -> kc 3..5, rows gidx)
      if (s < 53) {
#pragma unroll
        for (int kc2 = 0; kc2 < 3; kc2++)
#pragma unroll
          for (int rt = 0; rt < 2; rt++)
            afn[rt][kc2] = *(const bf16x8*)(vpad + (size_t)gidx[rt] * CINC +
                                            (kc2 + 3) * 32 + quad * 8);
      }
    } else {
      // prefetch A for stage s+1 (half0 of off+1 -> kc 0..2, rows gidx2)
      if (s < 53) {
#pragma unroll
        for (int kc2 = 0; kc2 < 3; kc2++)
#pragma unroll
          for (int rt = 0; rt < 2; rt++)
            afn[rt][kc2] = *(const bf16x8*)(vpad + (size_t)gidx2[rt] * CINC +
                                            kc2 * 32 + quad * 8);
      }
      gidx[0] = gidx2[0];
      gidx[1] = gidx2[1];
    }

    const char* bbr = (const char*)&Bb[buf][0];
#pragma unroll
    for (int kc2 = 0; kc2 < 3; kc2++) {
#pragma unroll
      for (int ct = 0; ct < 6; ct++) {
        bf16x8 bfm = *(const bf16x8*)(bbr + (size_t)(kc2 * 6 + ct) * 1024 + (size_t)lane * 16);
#pragma unroll
        for (int rt = 0; rt < 2; rt++)
          acc[rt][ct] = __builtin_amdgcn_mfma_f32_16x16x32_bf16(afc[rt][kc2], bfm, acc[rt][ct], 0, 0, 0);
      }
    }
  }

  // epilogue: plain stores (C layout: row = quad*4+rr, col = lane&15)
#pragma unroll
  for (int rt = 0; rt < 2; rt++) {
#pragma unroll
    for (int rr = 0; rr < 4; rr++) {
      const int r2 = rb + rt * 16 + quad * 4 + rr;
      if (r2 < M) {
        float* dst = accbuf + (size_t)r2 * HIDC + m;
#pragma unroll
        for (int ct = 0; ct < 6; ct++) dst[ct * 16] = acc[rt][ct][rr];
      }
    }
  }
}

// ---------------------------------------------------------------------------
// K3b: BN stats: column sums + sumsq over accbuf -> bnsum[0:96], bnsum[96:192]
// ---------------------------------------------------------------------------
__global__ void k_bnstat(const float* __restrict__ accbuf, float* __restrict__ bnsum,
                         int M) {
  const int tid = threadIdx.x;  // 192
  const int col = tid % 96;
  const int rp = tid / 96;
  float sv = 0.f, s2 = 0.f;
  for (int r = blockIdx.x * 2 + rp; r < M; r += gridDim.x * 2) {
    float v = accbuf[(size_t)r * HIDC + col];
    sv += v;
    s2 += v * v;
  }
  atomicAdd(bnsum + col, sv);
  atomicAdd(bnsum + 96 + col, s2);
}

// ---------------------------------------------------------------------------
// K4: finalize BN: scale = gamma*rsqrt(var+eps), shift = beta - mu*scale.
// ---------------------------------------------------------------------------
__global__ void k_bnfin(const float* __restrict__ bnsum, const float* __restrict__ gamma,
                        const float* __restrict__ beta, float* __restrict__ ss, int M) {
  int c = threadIdx.x;
  if (c >= 96) return;
  float inv = 1.0f / (float)M;
  float mu = bnsum[c] * inv;
  float var = bnsum[96 + c] * inv - mu * mu;
  var = fmaxf(var, 0.f);
  float sc = gamma[c] * rsqrtf(var + EPSC);
  ss[c] = sc;
  ss[96 + c] = beta[c] - mu * sc;
}

// ---------------------------------------------------------------------------
// K5: y = relu(acc*scale + shift) -> bf16 ypad, zero pad row M.
// ---------------------------------------------------------------------------
__global__ void k_bnapply(const float* __restrict__ accbuf, const float* __restrict__ ss,
                          bf16* __restrict__ ypad, int M) {
  int t = blockIdx.x * 256 + threadIdx.x;
  if (t >= (M + 1) * HIDC) return;
  int v = t / HIDC;
  int c = t - v * HIDC;
  float y = 0.f;
  if (v < M) y = fmaxf(accbuf[t] * ss[c] + ss[96 + c], 0.f);
  ypad[t] = (bf16)y;
}

// ---------------------------------------------------------------------------
// K6: lin = hx @ W_lin + b_lin (fp32 in, bf16 MFMA, bf16 out). LDS-free,
// 256 thr = 4 waves x 32 rows; B fragments direct from L2-resident wlpack
// (stage-padded layout: half = kc>=3).
// ---------------------------------------------------------------------------
__launch_bounds__(256, 4)
__global__ void k_linear(const float* __restrict__ hid, const float* __restrict__ qry,
                         const bf16* __restrict__ wlpack, const float* __restrict__ blin,
                         bf16* __restrict__ lin, int Npts) {
  const int tid = threadIdx.x;
  const int wave = tid >> 6;
  const int lane = tid & 63;
  const int m = lane & 15;
  const int quad = lane >> 4;
  const int rb = blockIdx.x * 128 + wave * 32;

  f32x4 acc[2][6];
#pragma unroll
  for (int rt = 0; rt < 2; rt++)
#pragma unroll
    for (int ct = 0; ct < 6; ct++) {
      f32x4 z = {0.f, 0.f, 0.f, 0.f};
      acc[rt][ct] = z;
    }

  int prow[2];
#pragma unroll
  for (int rt = 0; rt < 2; rt++) {
    int r = rb + rt * 16 + m;
    prow[rt] = (r < Npts) ? r : (Npts - 1);
  }
  const char* wp = (const char*)wlpack;
#pragma unroll
  for (int kc = 0; kc < 6; kc++) {
    const float* srcA = (kc < 3) ? (hid + kc * 32) : (qry + (kc - 3) * 32);
    bf16x8 af[2];
#pragma unroll
    for (int rt = 0; rt < 2; rt++) {
      const float* pA = srcA + (size_t)prow[rt] * HIDC + quad * 8;
      f32x4 lo = *(const f32x4*)pA;
      f32x4 hi = *(const f32x4*)(pA + 4);
#pragma unroll
      for (int j = 0; j < 4; j++) {
        af[rt][j] = (bf16)lo[j];
        af[rt][4 + j] = (bf16)hi[j];
      }
    }
    const int half = (kc >= 3) ? 1 : 0;
    const int kcl = kc - half * 3;
#pragma unroll
    for (int ct = 0; ct < 6; ct++) {
      bf16x8 bfm = *(const bf16x8*)(wp + (size_t)half * STG_B +
                                    (size_t)((kcl * 6 + ct) * 64 + lane) * 16);
#pragma unroll
      for (int rt = 0; rt < 2; rt++)
        acc[rt][ct] = __builtin_amdgcn_mfma_f32_16x16x32_bf16(af[rt], bfm, acc[rt][ct], 0, 0, 0);
    }
  }
  float bl[6];
#pragma unroll
  for (int ct = 0; ct < 6; ct++) bl[ct] = blin[ct * 16 + m];
#pragma unroll
  for (int rt = 0; rt < 2; rt++)
#pragma unroll
    for (int rr = 0; rr < 4; rr++) {
      const int r2 = rb + rt * 16 + quad * 4 + rr;
      if (r2 < Npts) {
        bf16* dst = lin + (size_t)r2 * HIDC + m;
#pragma unroll
        for (int ct = 0; ct < 6; ct++)
          dst[ct * 16] = (bf16)(acc[rt][ct][rr] + bl[ct]);
      }
    }
}

// ---------------------------------------------------------------------------
// K7: out = lin + sum_k w[p,k] * ypad[cidx[p,k]]  (8-channel groups)
// ---------------------------------------------------------------------------
__global__ void k_out(const bf16* __restrict__ lin, const bf16* __restrict__ ypad,
                      const float* __restrict__ cw, const int* __restrict__ cidx,
                      float* __restrict__ out, int Npts) {
  int t = blockIdx.x * 256 + threadIdx.x;
  if (t >= Npts * 12) return;
  int p = t / 12;
  int g = t - p * 12;
  float a[8];
  bf16x8 lv = *(const bf16x8*)(lin + (size_t)p * HIDC + g * 8);
#pragma unroll
  for (int j = 0; j < 8; j++) a[j] = (float)lv[j];
  f32x4 w0 = *(const f32x4*)(cw + (size_t)p * 8);
  f32x4 w1 = *(const f32x4*)(cw + (size_t)p * 8 + 4);
  const i32x4* cp = (const i32x4*)(cidx + (size_t)p * 8);
  i32x4 c0 = cp[0], c1 = cp[1];
#pragma unroll
  for (int k = 0; k < 8; k++) {
    int idx = (k < 4) ? c0[k] : c1[k - 4];
    float wk = (k < 4) ? w0[k] : w1[k - 4];
    bf16x8 yv = *(const bf16x8*)(ypad + (size_t)idx * HIDC + g * 8);
#pragma unroll
    for (int j = 0; j < 8; j++) a[j] += wk * (float)yv[j];
  }
  float* op = out + (size_t)p * HIDC + g * 8;
  f32x4 s0, s1;
#pragma unroll
  for (int j = 0; j < 4; j++) { s0[j] = a[j]; s1[j] = a[4 + j]; }
  *(f32x4*)op = s0;
  *(f32x4*)(op + 4) = s1;
}

// ---------------------------------------------------------------------------
extern "C" void kernel_launch(void* const* d_in, const int* in_sizes, int n_in,
                              void* d_out, int out_size, void* d_ws, size_t ws_size,
                              hipStream_t stream) {
  const float* hid = (const float*)d_in[0];
  const float* qry = (const float*)d_in[1];
  const float* Wc = (const float*)d_in[2];
  const float* gamma = (const float*)d_in[3];
  const float* beta = (const float*)d_in[4];
  const float* Wl = (const float*)d_in[5];
  const float* blin = (const float*)d_in[6];
  const float* cw = (const float*)d_in[7];
  const int* seg = (const int*)d_in[8];
  const int* nbr = (const int*)d_in[9];
  const int* cidx = (const int*)d_in[10];
  float* out = (float*)d_out;
  const int Npts = in_sizes[0] / HIDC;
  const int M = in_sizes[9] / 27;

  // ---- workspace layout ----
  // [cnt | bnsum]  <- single memset
  // region A: accbuf fp32 [M,96] (K3..K5) -> lin bf16 [N,96] (K6-K7) overlay
  // region B: vpad bf16 [M+1,192] (gmean..conv) -> ypad bf16 [M+1,96] overlay
  char* ws = (char*)d_ws;
  size_t cur = 0;
  auto alloc = [&](size_t b) { size_t o = cur; cur = (cur + b + 255) & ~(size_t)255; return o; };
  size_t o_cnt = alloc((size_t)M * 4);
  size_t o_bn = alloc(192 * 4);
  size_t o_ss = alloc(192 * 4);
  size_t o_ptr = alloc((size_t)M * 4);
  size_t o_cur = alloc((size_t)M * 4);
  size_t o_pl = alloc((size_t)Npts * 4);
  size_t o_bs = alloc(1024 * 4);
  size_t RA = (size_t)M * HIDC * 4;
  size_t needA = (size_t)Npts * HIDC * 2;
  if (needA > RA) RA = needA;
  size_t o_A = alloc(RA);
  size_t o_B = alloc((size_t)(M + 1) * CINC * 2);
  size_t o_wpack = alloc((size_t)56 * STG_B);
  (void)ws_size; (void)n_in; (void)out_size;

  int* cnt = (int*)(ws + o_cnt);
  float* bnsum = (float*)(ws + o_bn);
  float* ss = (float*)(ws + o_ss);
  int* ptr = (int*)(ws + o_ptr);
  int* cursor = (int*)(ws + o_cur);
  int* plist = (int*)(ws + o_pl);
  int* bsum = (int*)(ws + o_bs);
  float* accbuf = (float*)(ws + o_A);
  bf16* lin = (bf16*)(ws + o_A);
  bf16* vpad = (bf16*)(ws + o_B);
  bf16* ypad = (bf16*)(ws + o_B);
  bf16* wpack = (bf16*)(ws + o_wpack);
  bf16* wlpack = (bf16*)(ws + o_wpack + (size_t)54 * STG_B);

  // zero cnt + bnsum (adjacent at front; ws poisoned 0xAA each call)
  hipMemsetAsync(ws, 0, o_ss, stream);

  int totalRepack = 28 * 18432;
  k_repack<<<(totalRepack + 255) / 256, 256, 0, stream>>>(Wc, Wl, wpack, totalRepack);

  // voxelize: count -> scan -> scatter -> gather-mean
  int nb = (M + 255) / 256;
  k_count<<<(Npts + 255) / 256, 256, 0, stream>>>(seg, cnt, Npts);
  k_bsum<<<nb, 256, 0, stream>>>(cnt, bsum, M);
  k_bscan<<<1, 1024, 0, stream>>>(bsum, nb);
  k_ptr<<<nb, 256, 0, stream>>>(cnt, bsum, ptr, cursor, M);
  k_scatter<<<(Npts + 255) / 256, 256, 0, stream>>>(seg, cursor, plist, Npts);
  k_gmean<<<(((M + 1) * 48) + 255) / 256, 256, 0, stream>>>(hid, qry, ptr, cnt, plist, vpad, M);

  int nblk = (M + 127) / 128;
  int nper = (nblk + 7) / 8;
  k_conv<<<nper * 8, 256, 0, stream>>>(vpad, nbr, wpack, accbuf, M, nblk, nper);
  k_bnstat<<<256, 192, 0, stream>>>(accbuf, bnsum, M);
  k_bnfin<<<1, 128, 0, stream>>>(bnsum, gamma, beta, ss, M);
  k_bnapply<<<((M + 1) * HIDC + 255) / 256, 256, 0, stream>>>(accbuf, ss, ypad, M);
  k_linear<<<(Npts + 127) / 128, 256, 0, stream>>>(hid, qry, wlpack, blin, lin, Npts);
  k_out<<<(Npts * 12 + 255) / 256, 256, 0, stream>>>(lin, ypad, cw, cidx, out, Npts);
}